// Round 6
// baseline (557.119 us; speedup 1.0000x reference)
//
#include <hip/hip_runtime.h>
#include <math.h>

#define IMG_H 3072
#define IMG_W 4096
#define Hh 1536
#define Wh 2048
#define S (Hh*Wh)   // 3,145,728 per-plane pixels

#define TID 24   // rows/thread, fused denoise
#define TIL 16   // rows/thread, LTM box (r=8)

#if __has_builtin(__builtin_amdgcn_rcpf)
#define RCP(x) __builtin_amdgcn_rcpf(x)
#else
#define RCP(x) (1.0f/(x))
#endif

__device__ __forceinline__ float clamp01(float v){ return fminf(fmaxf(v, 0.0f), 1.0f); }

// jnp.interp over knots (0,0),(0.25,0.5),(1,1) then black-level
__device__ __forceinline__ float decompand_black(float v){
  float y = (v <= 0.25f) ? (2.0f*v) : fmaf(v - 0.25f, 0.5f/0.75f, 0.5f);
  y = clamp01(y);
  return clamp01((y - 0.0625f) * (1.0f/0.9375f));
}

// x^(1/2.2): v_log_f32 + v_exp_f32 (__builtin_amdgcn_logf IS log2)
__device__ __forceinline__ float gamma22(float x){
  return __builtin_amdgcn_exp2f(0.45454545454545453f * __builtin_amdgcn_logf(x));
}

// ---- K1: decompand + split into 4 RGGB planes ----
__global__ __launch_bounds__(256) void k_split(const float* __restrict__ x, float* __restrict__ P){
  int idx = blockIdx.x*256 + threadIdx.x;
  int i = idx >> 11, j = idx & 2047;
  const float* r0 = x + (2*i)*IMG_W + 2*j;
  const float* r1 = r0 + IMG_W;
  float2 a = *(const float2*)r0;
  float2 b = *(const float2*)r1;
  P[idx]       = decompand_black(a.x);
  P[S + idx]   = decompand_black(a.y);
  P[2*S + idx] = decompand_black(b.x);
  P[3*S + idx] = decompand_black(b.y);
}

// ---- fused guided-filter denoise (r=2, eps=100): both box passes register-resident ----
// FAST: all windows interior (count 25), all loads unguarded.
template<int TI, bool FAST>
__device__ __forceinline__ void denoise_col(const float* __restrict__ in, float* __restrict__ D,
                                            int j, int i0, float& local){
  const float inv25 = 1.0f/25.0f;
  float cw_a[5], amask[5], cw_o = 25.f;
  if (!FAST){
    #pragma unroll
    for (int k=0;k<5;++k){
      int pc = j + k - 2;
      bool ok = ((unsigned)pc < (unsigned)Wh);
      amask[k] = ok ? 1.f : 0.f;
      cw_a[k]  = ok ? (float)(min(pc+2, Wh-1) - max(pc-2, 0) + 1) : 1.f;
    }
    cw_o = (float)(min(j+2, Wh-1) - max(j-2, 0) + 1);
  }

  float rh1[5][5]={{0}}, rh2[5][5]={{0}};
  float vs1[5]={0}, vs2[5]={0};
  float rha[5]={0}, rhb[5]={0};
  float cI[5]={0};
  float wa=0.f, wb=0.f;

  #pragma unroll
  for (int rr=0; rr<TI+8; ++rr){
    int r = i0 - 4 + rr;
    float v[9];
    if (FAST){
      const float* rp = in + (size_t)r*Wh + j;
      #pragma unroll
      for (int d=0; d<9; ++d) v[d] = rp[d-4];
    } else {
      if ((unsigned)r < (unsigned)Hh){
        const float* rp = in + (size_t)r*Wh;
        #pragma unroll
        for (int d=0; d<9; ++d){
          int c = j + d - 4;
          v[d] = ((unsigned)c < (unsigned)Wh) ? rp[c] : 0.f;
        }
      } else {
        #pragma unroll
        for (int d=0; d<9; ++d) v[d]=0.f;
      }
    }
    float sq[9];
    #pragma unroll
    for (int d=0; d<9; ++d) sq[d]=v[d]*v[d];
    float h1[5], h2[5];
    h1[0]=v[0]+v[1]+v[2]+v[3]+v[4];
    h2[0]=sq[0]+sq[1]+sq[2]+sq[3]+sq[4];
    #pragma unroll
    for (int k=1;k<5;++k){
      h1[k]=h1[k-1]-v[k-1]+v[k+4];
      h2[k]=h2[k-1]-sq[k-1]+sq[k+4];
    }
    #pragma unroll
    for (int k=0;k<5;++k){
      vs1[k]+=h1[k]-rh1[k][0];
      vs2[k]+=h2[k]-rh2[k][0];
      #pragma unroll
      for (int t=0;t<4;++t){ rh1[k][t]=rh1[k][t+1]; rh2[k][t]=rh2[k][t+1]; }
      rh1[k][4]=h1[k]; rh2[k][4]=h2[k];
    }
    #pragma unroll
    for (int t=0;t<4;++t) cI[t]=cI[t+1];
    cI[4]=v[4];

    if (rr >= 4){
      int q = r-2;
      float ha_=0.f, hb_=0.f;
      if (FAST){
        #pragma unroll
        for (int k=0;k<5;++k){
          float m   = vs1[k]*inv25;
          float var = fmaf(-m, m, vs2[k]*inv25);
          float a   = var*RCP(var + 100.0f);
          float b   = fmaf(-m, a, m);
          ha_ += a; hb_ += b;
        }
      } else {
        float rmask = ((unsigned)q < (unsigned)Hh) ? 1.f : 0.f;
        float rh = (float)(min(q+2, Hh-1) - max(q-2, 0) + 1);
        #pragma unroll
        for (int k=0;k<5;++k){
          float inv = RCP(rh*cw_a[k]);
          float m   = vs1[k]*inv;
          float var = fmaf(-m, m, vs2[k]*inv);
          float a   = var*RCP(var + 100.0f);
          float b   = fmaf(-m, a, m);
          ha_ = fmaf(a, amask[k], ha_);
          hb_ = fmaf(b, amask[k], hb_);
        }
        ha_ *= rmask; hb_ *= rmask;
      }
      wa += ha_ - rha[0];
      wb += hb_ - rhb[0];
      #pragma unroll
      for (int t=0;t<4;++t){ rha[t]=rha[t+1]; rhb[t]=rhb[t+1]; }
      rha[4]=ha_; rhb[4]=hb_;

      if (rr >= 8){
        int ro = r-4;
        float invo;
        if (FAST){
          invo = inv25;
        } else {
          float rho = (float)(min(ro+2, Hh-1) - max(ro-2, 0) + 1);
          invo = RCP(rho*cw_o);
        }
        float d = fmaf(wa*invo, cI[0], wb*invo);
        D[(size_t)ro*Wh + j] = d;
        local += d;
      }
    }
  }
}

template<int TI>
__global__ __launch_bounds__(256) void k_denoise(const float* __restrict__ P4,
                                                 float* __restrict__ D4,
                                                 float* __restrict__ sums){
  const int j  = blockIdx.x*256 + threadIdx.x;
  const int i0 = blockIdx.y*TI;
  const int pl = blockIdx.z;
  const float* __restrict__ in = P4 + (size_t)pl*S;
  float* __restrict__ D = D4 + (size_t)pl*S;
  float local = 0.f;

  const bool fast = (blockIdx.x >= 1) && (blockIdx.x <= (Wh/256)-2) &&
                    (blockIdx.y >= 1) && (i0 + TI + 4 <= Hh);
  if (fast) denoise_col<TI, true >(in, D, j, i0, local);
  else      denoise_col<TI, false>(in, D, j, i0, local);

  __shared__ float red[256];
  red[threadIdx.x]=local;
  __syncthreads();
  #pragma unroll
  for (int off=128; off>0; off>>=1){
    if (threadIdx.x<off) red[threadIdx.x]+=red[threadIdx.x+off];
    __syncthreads();
  }
  if (threadIdx.x==0) atomicAdd(sums+pl, red[0]);
}

// ---- LTM box pass 1 (r=8) ----
template<int R, int TI>
__global__ __launch_bounds__(256) void k_boxsq_ab(const float* __restrict__ in,
                                                  float* __restrict__ A, float* __restrict__ B,
                                                  float eps){
  int j  = blockIdx.x*256 + threadIdx.x;
  int i0 = blockIdx.y*TI;
  int cw = min(j+R, Wh-1) - max(j-R, 0) + 1;

  float hs[2*R+1], hs2[2*R+1];
  float ws = 0.f, ws2 = 0.f;
  #pragma unroll
  for (int k=0; k<2*R+1; ++k){
    int r = i0 - R + k;
    float s = 0.f, s2 = 0.f;
    if ((unsigned)r < (unsigned)Hh){
      const float* row = in + r*Wh;
      #pragma unroll
      for (int d=-R; d<=R; ++d){
        int c = j + d;
        float v = ((unsigned)c < (unsigned)Wh) ? row[c] : 0.f;
        s += v; s2 = fmaf(v, v, s2);
      }
    }
    hs[k] = s; hs2[k] = s2; ws += s; ws2 += s2;
  }
  #pragma unroll
  for (int t=0; t<TI; ++t){
    int i = i0 + t;
    int rh = min(i+R, Hh-1) - max(i-R, 0) + 1;
    float inv = 1.0f/(float)(rh*cw);
    float m   = ws*inv;
    float var = fmaf(-m, m, ws2*inv);
    float a   = var/(var + eps);
    A[i*Wh + j] = a;
    B[i*Wh + j] = m*(1.0f - a);
    if (t < TI-1){
      ws -= hs[0]; ws2 -= hs2[0];
      #pragma unroll
      for (int k=0; k<2*R; ++k){ hs[k]=hs[k+1]; hs2[k]=hs2[k+1]; }
      int r = i + R + 1;
      float s = 0.f, s2 = 0.f;
      if (r < Hh){
        const float* row = in + r*Wh;
        #pragma unroll
        for (int d=-R; d<=R; ++d){
          int c = j + d;
          float v = ((unsigned)c < (unsigned)Wh) ? row[c] : 0.f;
          s += v; s2 = fmaf(v, v, s2);
        }
      }
      hs[2*R] = s; hs2[2*R] = s2; ws += s; ws2 += s2;
    }
  }
}

// ---- LTM box pass 2 (r=8) ----
template<int R, int TI>
__global__ __launch_bounds__(256) void k_box_apply(const float* __restrict__ in,
                                                   const float* __restrict__ A, const float* __restrict__ B,
                                                   float* __restrict__ D){
  int j  = blockIdx.x*256 + threadIdx.x;
  int i0 = blockIdx.y*TI;
  int cw = min(j+R, Wh-1) - max(j-R, 0) + 1;

  float ha[2*R+1], hb[2*R+1];
  float wa = 0.f, wb = 0.f;
  #pragma unroll
  for (int k=0; k<2*R+1; ++k){
    int r = i0 - R + k;
    float sa = 0.f, sb = 0.f;
    if ((unsigned)r < (unsigned)Hh){
      const float* ra = A + r*Wh;
      const float* rb = B + r*Wh;
      #pragma unroll
      for (int d=-R; d<=R; ++d){
        int c = j + d;
        bool ok = ((unsigned)c < (unsigned)Wh);
        sa += ok ? ra[c] : 0.f;
        sb += ok ? rb[c] : 0.f;
      }
    }
    ha[k] = sa; hb[k] = sb; wa += sa; wb += sb;
  }
  #pragma unroll
  for (int t=0; t<TI; ++t){
    int i = i0 + t;
    int rh = min(i+R, Hh-1) - max(i-R, 0) + 1;
    float inv = 1.0f/(float)(rh*cw);
    D[i*Wh + j] = fmaf(wa*inv, in[i*Wh + j], wb*inv);
    if (t < TI-1){
      wa -= ha[0]; wb -= hb[0];
      #pragma unroll
      for (int k=0; k<2*R; ++k){ ha[k]=ha[k+1]; hb[k]=hb[k+1]; }
      int r = i + R + 1;
      float sa = 0.f, sb = 0.f;
      if (r < Hh){
        const float* ra = A + r*Wh;
        const float* rb = B + r*Wh;
        #pragma unroll
        for (int d2=-R; d2<=R; ++d2){
          int c = j + d2;
          bool ok = ((unsigned)c < (unsigned)Wh);
          sa += ok ? ra[c] : 0.f;
          sb += ok ? rb[c] : 0.f;
        }
      }
      ha[2*R] = sa; hb[2*R] = sb; wa += sa; wb += sb;
    }
  }
}

// ---- AWB gains ----
__global__ void k_gains(const float* __restrict__ sums, float* __restrict__ gains){
  if (threadIdx.x == 0 && blockIdx.x == 0){
    const float inv = 1.0f/(float)S;
    float rm = sums[0]*inv, g1 = sums[1]*inv, g2 = sums[2]*inv, bm = sums[3]*inv;
    float gm = 0.5f*(g1+g2);
    gains[0] = fminf(gm/(rm + 1e-8f), 4.0f);
    gains[1] = fminf(gm/(bm + 1e-8f), 4.0f);
  }
}

// ---- gather 4x4 mosaic window (rows 2i-1..2i+2, cols 2j-1..2j+2) straight from D planes ----
// mosaic(y,x) = clamp01(D_plane[(y&1)*2+(x&1)][y>>1][x>>1] * gain); zero outside (conv zero-pad).
__device__ __forceinline__ void load_mosaic(const float* __restrict__ D, float gr, float gb,
                                            int i, int j, float m[4][4]){
  const float* __restrict__ P0 = D;
  const float* __restrict__ P1 = D + (size_t)S;
  const float* __restrict__ P2 = D + (size_t)2*S;
  const float* __restrict__ P3 = D + (size_t)3*S;
  const bool up = (i > 0), dn = (i < Hh-1), lf = (j > 0), rt = (j < Wh-1);
  const size_t rc = (size_t)i*Wh + j;
  const size_t ru = rc - Wh, rd = rc + Wh;
  // row y=2i-1 (odd): p3 (odd x) / p2 (even x), plane row i-1
  m[0][0] = (up && lf) ? clamp01(P3[ru-1]*gb) : 0.f;
  m[0][1] = up ? clamp01(P2[ru]) : 0.f;
  m[0][2] = up ? clamp01(P3[ru]*gb) : 0.f;
  m[0][3] = (up && rt) ? clamp01(P2[ru+1]) : 0.f;
  // row y=2i (even): p1 (odd x) / p0 (even x), plane row i
  m[1][0] = lf ? clamp01(P1[rc-1]) : 0.f;
  m[1][1] = clamp01(P0[rc]*gr);
  m[1][2] = clamp01(P1[rc]);
  m[1][3] = rt ? clamp01(P0[rc+1]*gr) : 0.f;
  // row y=2i+1 (odd): p3/p2, plane row i
  m[2][0] = lf ? clamp01(P3[rc-1]*gb) : 0.f;
  m[2][1] = clamp01(P2[rc]);
  m[2][2] = clamp01(P3[rc]*gb);
  m[2][3] = rt ? clamp01(P2[rc+1]) : 0.f;
  // row y=2i+2 (even): p1/p0, plane row i+1
  m[3][0] = (dn && lf) ? clamp01(P1[rd-1]) : 0.f;
  m[3][1] = dn ? clamp01(P0[rd]*gr) : 0.f;
  m[3][2] = dn ? clamp01(P1[rd]) : 0.f;
  m[3][3] = (dn && rt) ? clamp01(P0[rd+1]*gr) : 0.f;
}

__device__ __forceinline__ void demosaic_ccm(const float m[4][4], const float* __restrict__ C,
                                             float R[2][2], float G[2][2], float Bv[2][2]){
  float r[2][2], g[2][2], b[2][2];
  r[0][0] = m[1][1];
  g[0][0] = 0.25f*(m[0][1]+m[2][1]+m[1][0]+m[1][2]);
  b[0][0] = 0.25f*(m[0][0]+m[0][2]+m[2][0]+m[2][2]);
  r[0][1] = 0.5f*(m[1][1]+m[1][3]);
  g[0][1] = m[1][2];
  b[0][1] = 0.5f*(m[0][2]+m[2][2]);
  r[1][0] = 0.5f*(m[1][1]+m[3][1]);
  g[1][0] = m[2][1];
  b[1][0] = 0.5f*(m[2][0]+m[2][2]);
  r[1][1] = 0.25f*(m[1][1]+m[1][3]+m[3][1]+m[3][3]);
  g[1][1] = 0.25f*(m[1][2]+m[3][2]+m[2][1]+m[2][3]);
  b[1][1] = m[2][2];
  #pragma unroll
  for (int a=0; a<2; ++a){
    #pragma unroll
    for (int c=0; c<2; ++c){
      R[a][c]  = clamp01(fmaf(C[2], b[a][c], fmaf(C[1], g[a][c], C[0]*r[a][c])));
      G[a][c]  = clamp01(fmaf(C[5], b[a][c], fmaf(C[4], g[a][c], C[3]*r[a][c])));
      Bv[a][c] = clamp01(fmaf(C[8], b[a][c], fmaf(C[7], g[a][c], C[6]*r[a][c])));
    }
  }
}

// ---- half-res luma Ys (reads D planes + gains directly) ----
__global__ __launch_bounds__(256) void k_ys(const float* __restrict__ D, const float* __restrict__ gains,
                                            const float* __restrict__ C, float* __restrict__ Ys){
  int idx = blockIdx.x*256 + threadIdx.x;
  int i = idx >> 11, j = idx & 2047;
  float gr = gains[0], gb = gains[1];
  float m[4][4]; load_mosaic(D, gr, gb, i, j, m);
  float R[2][2], G[2][2], Bv[2][2];
  demosaic_ccm(m, C, R, G, Bv);
  float y = 0.f;
  #pragma unroll
  for (int a=0; a<2; ++a)
    #pragma unroll
    for (int c=0; c<2; ++c)
      y += 0.299f*R[a][c] + 0.587f*G[a][c] + 0.114f*Bv[a][c];
  Ys[idx] = 0.25f*y;
}

// ---- final: demosaic+CCM (from D planes) + LTM + gamma + RGB->YUV -> NV12 ----
__global__ __launch_bounds__(256) void k_final(const float* __restrict__ D, const float* __restrict__ gains,
                                               const float* __restrict__ C,
                                               const float* __restrict__ bs, float* __restrict__ out){
  int idx = blockIdx.x*256 + threadIdx.x;
  int i = idx >> 11, j = idx & 2047;
  float gr = gains[0], gb = gains[1];
  float m[4][4]; load_mosaic(D, gr, gb, i, j, m);
  float R[2][2], G[2][2], Bv[2][2];
  demosaic_ccm(m, C, R, G, Bv);

  float bsv[3][3];
  #pragma unroll
  for (int a=0; a<3; ++a){
    int r = min(max(i-1+a, 0), Hh-1);
    #pragma unroll
    for (int b=0; b<3; ++b){
      int c = min(max(j-1+b, 0), Wh-1);
      bsv[a][b] = bs[(r<<11) + c];
    }
  }
  float base[2][2];
  base[0][0] = 0.0625f*bsv[0][0] + 0.1875f*bsv[0][1] + 0.1875f*bsv[1][0] + 0.5625f*bsv[1][1];
  base[0][1] = 0.1875f*bsv[0][1] + 0.0625f*bsv[0][2] + 0.5625f*bsv[1][1] + 0.1875f*bsv[1][2];
  base[1][0] = 0.1875f*bsv[1][0] + 0.5625f*bsv[1][1] + 0.0625f*bsv[2][0] + 0.1875f*bsv[2][1];
  base[1][1] = 0.5625f*bsv[1][1] + 0.1875f*bsv[1][2] + 0.1875f*bsv[2][1] + 0.0625f*bsv[2][2];

  float Yp[2][2];
  float Uacc = 0.f, Vacc = 0.f;
  #pragma unroll
  for (int a=0; a<2; ++a){
    #pragma unroll
    for (int c=0; c<2; ++c){
      float Yl   = 0.299f*R[a][c] + 0.587f*G[a][c] + 0.114f*Bv[a][c];
      float Ynew = fmaf(0.7f, base[a][c], Yl - base[a][c]);
      float sc   = Ynew/(Yl + 1e-6f);
      float Rg = gamma22(fmaxf(clamp01(R[a][c]*sc),  1e-6f));
      float Gg = gamma22(fmaxf(clamp01(G[a][c]*sc),  1e-6f));
      float Bg = gamma22(fmaxf(clamp01(Bv[a][c]*sc), 1e-6f));
      float Yf = 0.299f*Rg + 0.587f*Gg + 0.114f*Bg;
      Yp[a][c] = fminf(fmaxf(Yf*255.0f, 0.0f), 255.0f);
      Uacc += -0.168736f*Rg - 0.331264f*Gg + 0.5f*Bg + 0.5f;
      Vacc +=  0.5f*Rg - 0.418688f*Gg - 0.081312f*Bg + 0.5f;
    }
  }
  *(float2*)(out + (2*i)*IMG_W   + 2*j) = make_float2(Yp[0][0], Yp[0][1]);
  *(float2*)(out + (2*i+1)*IMG_W + 2*j) = make_float2(Yp[1][0], Yp[1][1]);
  float u = fminf(fmaxf(0.25f*Uacc*255.0f, 0.0f), 255.0f);
  float v = fminf(fmaxf(0.25f*Vacc*255.0f, 0.0f), 255.0f);
  *(float2*)(out + IMG_H*IMG_W + i*IMG_W + 2*j) = make_float2(u, v);
}

extern "C" void kernel_launch(void* const* d_in, const int* in_sizes, int n_in,
                              void* d_out, int out_size, void* d_ws, size_t ws_size,
                              hipStream_t stream){
  const float* x   = (const float*)d_in[0];
  const float* ccm = (const float*)d_in[1];
  float* ws  = (float*)d_ws;
  float* out = (float*)d_out;

  // workspace layout (floats), total 10*S + 8:
  //  [0,4S)   P (planes); free after k_denoise -> Lb=[0,S), bs=[S,2S)
  //  [4S,8S)  D (denoised planes) — live until k_final
  //  [8S,9S)  Ys
  //  [9S,10S) La
  //  [10S,+8) sums[4], gains[2]
  size_t need = ((size_t)10*S + 8)*sizeof(float);
  if (ws_size < need) return;

  float* P  = ws;
  float* D  = ws + (size_t)4*S;
  float* Ys = ws + (size_t)8*S;
  float* La = ws + (size_t)9*S;
  float* Lb = ws;                    // aliases P (dead after denoise)
  float* bs = ws + (size_t)S;
  float* sums  = ws + (size_t)10*S;
  float* gains = sums + 4;

  const int nb = S/256;
  dim3 gdn(Wh/256, Hh/TID, 4);              // fused denoise, all planes
  dim3 gltm(Wh/256, Hh/TIL);                // LTM box kernels

  k_split<<<nb, 256, 0, stream>>>(x, P);
  (void)hipMemsetAsync(sums, 0, 4*sizeof(float), stream);
  k_denoise<TID><<<gdn, 256, 0, stream>>>(P, D, sums);
  k_gains<<<1, 64, 0, stream>>>(sums, gains);
  k_ys<<<nb, 256, 0, stream>>>(D, gains, ccm, Ys);
  k_boxsq_ab<8, TIL><<<gltm, 256, 0, stream>>>(Ys, La, Lb, 1e-3f);
  k_box_apply<8, TIL><<<gltm, 256, 0, stream>>>(Ys, La, Lb, bs);
  k_final<<<nb, 256, 0, stream>>>(D, gains, ccm, bs, out);
}

// Round 7
// 329.816 us; speedup vs baseline: 1.6892x; 1.6892x over previous
//
#include <hip/hip_runtime.h>
#include <math.h>

#define IMG_H 3072
#define IMG_W 4096
#define Hh 1536
#define Wh 2048
#define S (Hh*Wh)   // 3,145,728 per-plane pixels

#define TID 32   // rows/thread, fused denoise (trip = TID+8 = 40, unroll 4)
#define TIL 16   // rows/thread, LTM box (r=8)

#if __has_builtin(__builtin_amdgcn_rcpf)
#define RCP(x) __builtin_amdgcn_rcpf(x)
#else
#define RCP(x) (1.0f/(x))
#endif

__device__ __forceinline__ float clamp01(float v){ return fminf(fmaxf(v, 0.0f), 1.0f); }

// jnp.interp over knots (0,0),(0.25,0.5),(1,1) then black-level
__device__ __forceinline__ float decompand_black(float v){
  float y = (v <= 0.25f) ? (2.0f*v) : fmaf(v - 0.25f, 0.5f/0.75f, 0.5f);
  y = clamp01(y);
  return clamp01((y - 0.0625f) * (1.0f/0.9375f));
}

// x^(1/2.2): v_log_f32 + v_exp_f32 (__builtin_amdgcn_logf IS log2)
__device__ __forceinline__ float gamma22(float x){
  return __builtin_amdgcn_exp2f(0.45454545454545453f * __builtin_amdgcn_logf(x));
}

// ---- K1: decompand + split into 4 RGGB planes ----
__global__ __launch_bounds__(256) void k_split(const float* __restrict__ x, float* __restrict__ P){
  int idx = blockIdx.x*256 + threadIdx.x;
  int i = idx >> 11, j = idx & 2047;
  const float* r0 = x + (2*i)*IMG_W + 2*j;
  const float* r1 = r0 + IMG_W;
  float2 a = *(const float2*)r0;
  float2 b = *(const float2*)r1;
  P[idx]       = decompand_black(a.x);
  P[S + idx]   = decompand_black(a.y);
  P[2*S + idx] = decompand_black(b.x);
  P[3*S + idx] = decompand_black(b.y);
}

// ---- fused guided-filter denoise (r=2, eps=100): both box passes register-resident ----
// FAST: all windows interior (count 25), all loads unguarded.
// unroll 4: ring shifts rename inside the group; live ranges stay bounded.
template<int TI, bool FAST>
__device__ __forceinline__ void denoise_col(const float* __restrict__ in, float* __restrict__ D,
                                            int j, int i0, float& local){
  const float inv25 = 1.0f/25.0f;
  float cw_a[5], amask[5], cw_o = 25.f;
  if (!FAST){
    #pragma unroll
    for (int k=0;k<5;++k){
      int pc = j + k - 2;
      bool ok = ((unsigned)pc < (unsigned)Wh);
      amask[k] = ok ? 1.f : 0.f;
      cw_a[k]  = ok ? (float)(min(pc+2, Wh-1) - max(pc-2, 0) + 1) : 1.f;
    }
    cw_o = (float)(min(j+2, Wh-1) - max(j-2, 0) + 1);
  }

  float rh1[5][5]={{0}}, rh2[5][5]={{0}};
  float vs1[5]={0}, vs2[5]={0};
  float rha[5]={0}, rhb[5]={0};
  float cI[5]={0};
  float wa=0.f, wb=0.f;

  const float* rp = in + (size_t)(i0-4)*Wh + j;   // row pointer, bumped by Wh per iter
  float* wp = D + (size_t)i0*Wh + j;              // output pointer (ro = i0 + rr-8)

  #pragma unroll 4
  for (int rr=0; rr<TI+8; ++rr){
    int r = i0 - 4 + rr;
    float v[9];
    if (FAST){
      #pragma unroll
      for (int d=0; d<9; ++d) v[d] = rp[d-4];
    } else {
      if ((unsigned)r < (unsigned)Hh){
        #pragma unroll
        for (int d=0; d<9; ++d){
          int c = j + d - 4;
          v[d] = ((unsigned)c < (unsigned)Wh) ? rp[d-4] : 0.f;
        }
      } else {
        #pragma unroll
        for (int d=0; d<9; ++d) v[d]=0.f;
      }
    }
    rp += Wh;
    float sq[9];
    #pragma unroll
    for (int d=0; d<9; ++d) sq[d]=v[d]*v[d];
    float h1[5], h2[5];
    h1[0]=v[0]+v[1]+v[2]+v[3]+v[4];
    h2[0]=sq[0]+sq[1]+sq[2]+sq[3]+sq[4];
    #pragma unroll
    for (int k=1;k<5;++k){
      h1[k]=h1[k-1]-v[k-1]+v[k+4];
      h2[k]=h2[k-1]-sq[k-1]+sq[k+4];
    }
    #pragma unroll
    for (int k=0;k<5;++k){
      vs1[k]+=h1[k]-rh1[k][0];
      vs2[k]+=h2[k]-rh2[k][0];
      #pragma unroll
      for (int t=0;t<4;++t){ rh1[k][t]=rh1[k][t+1]; rh2[k][t]=rh2[k][t+1]; }
      rh1[k][4]=h1[k]; rh2[k][4]=h2[k];
    }
    #pragma unroll
    for (int t=0;t<4;++t) cI[t]=cI[t+1];
    cI[4]=v[4];

    if (rr >= 4){
      int q = r-2;
      float ha_=0.f, hb_=0.f;
      if (FAST){
        #pragma unroll
        for (int k=0;k<5;++k){
          float m   = vs1[k]*inv25;
          float var = fmaf(-m, m, vs2[k]*inv25);
          float a   = var*RCP(var + 100.0f);
          float b   = fmaf(-m, a, m);
          ha_ += a; hb_ += b;
        }
      } else {
        float rmask = ((unsigned)q < (unsigned)Hh) ? 1.f : 0.f;
        float rh = (float)(min(q+2, Hh-1) - max(q-2, 0) + 1);
        #pragma unroll
        for (int k=0;k<5;++k){
          float inv = RCP(rh*cw_a[k]);
          float m   = vs1[k]*inv;
          float var = fmaf(-m, m, vs2[k]*inv);
          float a   = var*RCP(var + 100.0f);
          float b   = fmaf(-m, a, m);
          ha_ = fmaf(a, amask[k], ha_);
          hb_ = fmaf(b, amask[k], hb_);
        }
        ha_ *= rmask; hb_ *= rmask;
      }
      wa += ha_ - rha[0];
      wb += hb_ - rhb[0];
      #pragma unroll
      for (int t=0;t<4;++t){ rha[t]=rha[t+1]; rhb[t]=rhb[t+1]; }
      rha[4]=ha_; rhb[4]=hb_;

      if (rr >= 8){
        int ro = r-4;
        float invo;
        if (FAST){
          invo = inv25;
        } else {
          float rho = (float)(min(ro+2, Hh-1) - max(ro-2, 0) + 1);
          invo = RCP(rho*cw_o);
        }
        float d = fmaf(wa*invo, cI[0], wb*invo);
        *wp = d; wp += Wh;
        local += d;
      }
    }
  }
}

template<int TI>
__global__ __launch_bounds__(256) void k_denoise(const float* __restrict__ P4,
                                                 float* __restrict__ D4,
                                                 float* __restrict__ sums){
  const int j  = blockIdx.x*256 + threadIdx.x;
  const int i0 = blockIdx.y*TI;
  const int pl = blockIdx.z;
  const float* __restrict__ in = P4 + (size_t)pl*S;
  float* __restrict__ D = D4 + (size_t)pl*S;
  float local = 0.f;

  const bool fast = (blockIdx.x >= 1) && (blockIdx.x <= (Wh/256)-2) &&
                    (blockIdx.y >= 1) && (i0 + TI + 4 <= Hh);
  if (fast) denoise_col<TI, true >(in, D, j, i0, local);
  else      denoise_col<TI, false>(in, D, j, i0, local);

  __shared__ float red[256];
  red[threadIdx.x]=local;
  __syncthreads();
  #pragma unroll
  for (int off=128; off>0; off>>=1){
    if (threadIdx.x<off) red[threadIdx.x]+=red[threadIdx.x+off];
    __syncthreads();
  }
  if (threadIdx.x==0) atomicAdd(sums+pl, red[0]);
}

// ---- LTM box pass 1 (r=8) ----
template<int R, int TI>
__global__ __launch_bounds__(256) void k_boxsq_ab(const float* __restrict__ in,
                                                  float* __restrict__ A, float* __restrict__ B,
                                                  float eps){
  int j  = blockIdx.x*256 + threadIdx.x;
  int i0 = blockIdx.y*TI;
  int cw = min(j+R, Wh-1) - max(j-R, 0) + 1;

  float hs[2*R+1], hs2[2*R+1];
  float ws = 0.f, ws2 = 0.f;
  #pragma unroll
  for (int k=0; k<2*R+1; ++k){
    int r = i0 - R + k;
    float s = 0.f, s2 = 0.f;
    if ((unsigned)r < (unsigned)Hh){
      const float* row = in + r*Wh;
      #pragma unroll
      for (int d=-R; d<=R; ++d){
        int c = j + d;
        float v = ((unsigned)c < (unsigned)Wh) ? row[c] : 0.f;
        s += v; s2 = fmaf(v, v, s2);
      }
    }
    hs[k] = s; hs2[k] = s2; ws += s; ws2 += s2;
  }
  #pragma unroll
  for (int t=0; t<TI; ++t){
    int i = i0 + t;
    int rh = min(i+R, Hh-1) - max(i-R, 0) + 1;
    float inv = 1.0f/(float)(rh*cw);
    float m   = ws*inv;
    float var = fmaf(-m, m, ws2*inv);
    float a   = var/(var + eps);
    A[i*Wh + j] = a;
    B[i*Wh + j] = m*(1.0f - a);
    if (t < TI-1){
      ws -= hs[0]; ws2 -= hs2[0];
      #pragma unroll
      for (int k=0; k<2*R; ++k){ hs[k]=hs[k+1]; hs2[k]=hs2[k+1]; }
      int r = i + R + 1;
      float s = 0.f, s2 = 0.f;
      if (r < Hh){
        const float* row = in + r*Wh;
        #pragma unroll
        for (int d=-R; d<=R; ++d){
          int c = j + d;
          float v = ((unsigned)c < (unsigned)Wh) ? row[c] : 0.f;
          s += v; s2 = fmaf(v, v, s2);
        }
      }
      hs[2*R] = s; hs2[2*R] = s2; ws += s; ws2 += s2;
    }
  }
}

// ---- LTM box pass 2 (r=8) ----
template<int R, int TI>
__global__ __launch_bounds__(256) void k_box_apply(const float* __restrict__ in,
                                                   const float* __restrict__ A, const float* __restrict__ B,
                                                   float* __restrict__ D){
  int j  = blockIdx.x*256 + threadIdx.x;
  int i0 = blockIdx.y*TI;
  int cw = min(j+R, Wh-1) - max(j-R, 0) + 1;

  float ha[2*R+1], hb[2*R+1];
  float wa = 0.f, wb = 0.f;
  #pragma unroll
  for (int k=0; k<2*R+1; ++k){
    int r = i0 - R + k;
    float sa = 0.f, sb = 0.f;
    if ((unsigned)r < (unsigned)Hh){
      const float* ra = A + r*Wh;
      const float* rb = B + r*Wh;
      #pragma unroll
      for (int d=-R; d<=R; ++d){
        int c = j + d;
        bool ok = ((unsigned)c < (unsigned)Wh);
        sa += ok ? ra[c] : 0.f;
        sb += ok ? rb[c] : 0.f;
      }
    }
    ha[k] = sa; hb[k] = sb; wa += sa; wb += sb;
  }
  #pragma unroll
  for (int t=0; t<TI; ++t){
    int i = i0 + t;
    int rh = min(i+R, Hh-1) - max(i-R, 0) + 1;
    float inv = 1.0f/(float)(rh*cw);
    D[i*Wh + j] = fmaf(wa*inv, in[i*Wh + j], wb*inv);
    if (t < TI-1){
      wa -= ha[0]; wb -= hb[0];
      #pragma unroll
      for (int k=0; k<2*R; ++k){ ha[k]=ha[k+1]; hb[k]=hb[k+1]; }
      int r = i + R + 1;
      float sa = 0.f, sb = 0.f;
      if (r < Hh){
        const float* ra = A + r*Wh;
        const float* rb = B + r*Wh;
        #pragma unroll
        for (int d2=-R; d2<=R; ++d2){
          int c = j + d2;
          bool ok = ((unsigned)c < (unsigned)Wh);
          sa += ok ? ra[c] : 0.f;
          sb += ok ? rb[c] : 0.f;
        }
      }
      ha[2*R] = sa; hb[2*R] = sb; wa += sa; wb += sb;
    }
  }
}

// ---- AWB gains ----
__global__ void k_gains(const float* __restrict__ sums, float* __restrict__ gains){
  if (threadIdx.x == 0 && blockIdx.x == 0){
    const float inv = 1.0f/(float)S;
    float rm = sums[0]*inv, g1 = sums[1]*inv, g2 = sums[2]*inv, bm = sums[3]*inv;
    float gm = 0.5f*(g1+g2);
    gains[0] = fminf(gm/(rm + 1e-8f), 4.0f);
    gains[1] = fminf(gm/(bm + 1e-8f), 4.0f);
  }
}

// ---- gather 4x4 mosaic window (rows 2i-1..2i+2, cols 2j-1..2j+2) straight from D planes ----
__device__ __forceinline__ void load_mosaic(const float* __restrict__ D, float gr, float gb,
                                            int i, int j, float m[4][4]){
  const float* __restrict__ P0 = D;
  const float* __restrict__ P1 = D + (size_t)S;
  const float* __restrict__ P2 = D + (size_t)2*S;
  const float* __restrict__ P3 = D + (size_t)3*S;
  const bool up = (i > 0), dn = (i < Hh-1), lf = (j > 0), rt = (j < Wh-1);
  const size_t rc = (size_t)i*Wh + j;
  const size_t ru = rc - Wh, rd = rc + Wh;
  m[0][0] = (up && lf) ? clamp01(P3[ru-1]*gb) : 0.f;
  m[0][1] = up ? clamp01(P2[ru]) : 0.f;
  m[0][2] = up ? clamp01(P3[ru]*gb) : 0.f;
  m[0][3] = (up && rt) ? clamp01(P2[ru+1]) : 0.f;
  m[1][0] = lf ? clamp01(P1[rc-1]) : 0.f;
  m[1][1] = clamp01(P0[rc]*gr);
  m[1][2] = clamp01(P1[rc]);
  m[1][3] = rt ? clamp01(P0[rc+1]*gr) : 0.f;
  m[2][0] = lf ? clamp01(P3[rc-1]*gb) : 0.f;
  m[2][1] = clamp01(P2[rc]);
  m[2][2] = clamp01(P3[rc]*gb);
  m[2][3] = rt ? clamp01(P2[rc+1]) : 0.f;
  m[3][0] = (dn && lf) ? clamp01(P1[rd-1]) : 0.f;
  m[3][1] = dn ? clamp01(P0[rd]*gr) : 0.f;
  m[3][2] = dn ? clamp01(P1[rd]) : 0.f;
  m[3][3] = (dn && rt) ? clamp01(P0[rd+1]*gr) : 0.f;
}

__device__ __forceinline__ void demosaic_ccm(const float m[4][4], const float* __restrict__ C,
                                             float R[2][2], float G[2][2], float Bv[2][2]){
  float r[2][2], g[2][2], b[2][2];
  r[0][0] = m[1][1];
  g[0][0] = 0.25f*(m[0][1]+m[2][1]+m[1][0]+m[1][2]);
  b[0][0] = 0.25f*(m[0][0]+m[0][2]+m[2][0]+m[2][2]);
  r[0][1] = 0.5f*(m[1][1]+m[1][3]);
  g[0][1] = m[1][2];
  b[0][1] = 0.5f*(m[0][2]+m[2][2]);
  r[1][0] = 0.5f*(m[1][1]+m[3][1]);
  g[1][0] = m[2][1];
  b[1][0] = 0.5f*(m[2][0]+m[2][2]);
  r[1][1] = 0.25f*(m[1][1]+m[1][3]+m[3][1]+m[3][3]);
  g[1][1] = 0.25f*(m[1][2]+m[3][2]+m[2][1]+m[2][3]);
  b[1][1] = m[2][2];
  #pragma unroll
  for (int a=0; a<2; ++a){
    #pragma unroll
    for (int c=0; c<2; ++c){
      R[a][c]  = clamp01(fmaf(C[2], b[a][c], fmaf(C[1], g[a][c], C[0]*r[a][c])));
      G[a][c]  = clamp01(fmaf(C[5], b[a][c], fmaf(C[4], g[a][c], C[3]*r[a][c])));
      Bv[a][c] = clamp01(fmaf(C[8], b[a][c], fmaf(C[7], g[a][c], C[6]*r[a][c])));
    }
  }
}

// ---- half-res luma Ys (reads D planes + gains directly) ----
__global__ __launch_bounds__(256) void k_ys(const float* __restrict__ D, const float* __restrict__ gains,
                                            const float* __restrict__ C, float* __restrict__ Ys){
  int idx = blockIdx.x*256 + threadIdx.x;
  int i = idx >> 11, j = idx & 2047;
  float gr = gains[0], gb = gains[1];
  float m[4][4]; load_mosaic(D, gr, gb, i, j, m);
  float R[2][2], G[2][2], Bv[2][2];
  demosaic_ccm(m, C, R, G, Bv);
  float y = 0.f;
  #pragma unroll
  for (int a=0; a<2; ++a)
    #pragma unroll
    for (int c=0; c<2; ++c)
      y += 0.299f*R[a][c] + 0.587f*G[a][c] + 0.114f*Bv[a][c];
  Ys[idx] = 0.25f*y;
}

// ---- final: demosaic+CCM (from D planes) + LTM + gamma + RGB->YUV -> NV12 ----
__global__ __launch_bounds__(256) void k_final(const float* __restrict__ D, const float* __restrict__ gains,
                                               const float* __restrict__ C,
                                               const float* __restrict__ bs, float* __restrict__ out){
  int idx = blockIdx.x*256 + threadIdx.x;
  int i = idx >> 11, j = idx & 2047;
  float gr = gains[0], gb = gains[1];
  float m[4][4]; load_mosaic(D, gr, gb, i, j, m);
  float R[2][2], G[2][2], Bv[2][2];
  demosaic_ccm(m, C, R, G, Bv);

  float bsv[3][3];
  #pragma unroll
  for (int a=0; a<3; ++a){
    int r = min(max(i-1+a, 0), Hh-1);
    #pragma unroll
    for (int b=0; b<3; ++b){
      int c = min(max(j-1+b, 0), Wh-1);
      bsv[a][b] = bs[(r<<11) + c];
    }
  }
  float base[2][2];
  base[0][0] = 0.0625f*bsv[0][0] + 0.1875f*bsv[0][1] + 0.1875f*bsv[1][0] + 0.5625f*bsv[1][1];
  base[0][1] = 0.1875f*bsv[0][1] + 0.0625f*bsv[0][2] + 0.5625f*bsv[1][1] + 0.1875f*bsv[1][2];
  base[1][0] = 0.1875f*bsv[1][0] + 0.5625f*bsv[1][1] + 0.0625f*bsv[2][0] + 0.1875f*bsv[2][1];
  base[1][1] = 0.5625f*bsv[1][1] + 0.1875f*bsv[1][2] + 0.1875f*bsv[2][1] + 0.0625f*bsv[2][2];

  float Yp[2][2];
  float Uacc = 0.f, Vacc = 0.f;
  #pragma unroll
  for (int a=0; a<2; ++a){
    #pragma unroll
    for (int c=0; c<2; ++c){
      float Yl   = 0.299f*R[a][c] + 0.587f*G[a][c] + 0.114f*Bv[a][c];
      float Ynew = fmaf(0.7f, base[a][c], Yl - base[a][c]);
      float sc   = Ynew/(Yl + 1e-6f);
      float Rg = gamma22(fmaxf(clamp01(R[a][c]*sc),  1e-6f));
      float Gg = gamma22(fmaxf(clamp01(G[a][c]*sc),  1e-6f));
      float Bg = gamma22(fmaxf(clamp01(Bv[a][c]*sc), 1e-6f));
      float Yf = 0.299f*Rg + 0.587f*Gg + 0.114f*Bg;
      Yp[a][c] = fminf(fmaxf(Yf*255.0f, 0.0f), 255.0f);
      Uacc += -0.168736f*Rg - 0.331264f*Gg + 0.5f*Bg + 0.5f;
      Vacc +=  0.5f*Rg - 0.418688f*Gg - 0.081312f*Bg + 0.5f;
    }
  }
  *(float2*)(out + (2*i)*IMG_W   + 2*j) = make_float2(Yp[0][0], Yp[0][1]);
  *(float2*)(out + (2*i+1)*IMG_W + 2*j) = make_float2(Yp[1][0], Yp[1][1]);
  float u = fminf(fmaxf(0.25f*Uacc*255.0f, 0.0f), 255.0f);
  float v = fminf(fmaxf(0.25f*Vacc*255.0f, 0.0f), 255.0f);
  *(float2*)(out + IMG_H*IMG_W + i*IMG_W + 2*j) = make_float2(u, v);
}

extern "C" void kernel_launch(void* const* d_in, const int* in_sizes, int n_in,
                              void* d_out, int out_size, void* d_ws, size_t ws_size,
                              hipStream_t stream){
  const float* x   = (const float*)d_in[0];
  const float* ccm = (const float*)d_in[1];
  float* ws  = (float*)d_ws;
  float* out = (float*)d_out;

  // workspace layout (floats), total 10*S + 8:
  //  [0,4S)   P (planes); free after k_denoise -> Lb=[0,S), bs=[S,2S)
  //  [4S,8S)  D (denoised planes) — live until k_final
  //  [8S,9S)  Ys
  //  [9S,10S) La
  //  [10S,+8) sums[4], gains[2]
  size_t need = ((size_t)10*S + 8)*sizeof(float);
  if (ws_size < need) return;

  float* P  = ws;
  float* D  = ws + (size_t)4*S;
  float* Ys = ws + (size_t)8*S;
  float* La = ws + (size_t)9*S;
  float* Lb = ws;                    // aliases P (dead after denoise)
  float* bs = ws + (size_t)S;
  float* sums  = ws + (size_t)10*S;
  float* gains = sums + 4;

  const int nb = S/256;
  dim3 gdn(Wh/256, Hh/TID, 4);              // fused denoise, all planes
  dim3 gltm(Wh/256, Hh/TIL);                // LTM box kernels

  k_split<<<nb, 256, 0, stream>>>(x, P);
  (void)hipMemsetAsync(sums, 0, 4*sizeof(float), stream);
  k_denoise<TID><<<gdn, 256, 0, stream>>>(P, D, sums);
  k_gains<<<1, 64, 0, stream>>>(sums, gains);
  k_ys<<<nb, 256, 0, stream>>>(D, gains, ccm, Ys);
  k_boxsq_ab<8, TIL><<<gltm, 256, 0, stream>>>(Ys, La, Lb, 1e-3f);
  k_box_apply<8, TIL><<<gltm, 256, 0, stream>>>(Ys, La, Lb, bs);
  k_final<<<nb, 256, 0, stream>>>(D, gains, ccm, bs, out);
}

// Round 8
// 320.401 us; speedup vs baseline: 1.7388x; 1.0294x over previous
//
#include <hip/hip_runtime.h>
#include <math.h>

#define IMG_H 3072
#define IMG_W 4096
#define Hh 1536
#define Wh 2048
#define S (Hh*Wh)   // 3,145,728 per-plane pixels

#define TID 32   // rows/thread, fused denoise (trip = TID+8 = 40, unroll 4)
#define TIL 16   // rows/thread, LTM box (r=8)

#if __has_builtin(__builtin_amdgcn_rcpf)
#define RCP(x) __builtin_amdgcn_rcpf(x)
#else
#define RCP(x) (1.0f/(x))
#endif

__device__ __forceinline__ float clamp01(float v){ return fminf(fmaxf(v, 0.0f), 1.0f); }

// jnp.interp over knots (0,0),(0.25,0.5),(1,1) then black-level
__device__ __forceinline__ float decompand_black(float v){
  float y = (v <= 0.25f) ? (2.0f*v) : fmaf(v - 0.25f, 0.5f/0.75f, 0.5f);
  y = clamp01(y);
  return clamp01((y - 0.0625f) * (1.0f/0.9375f));
}

// x^(1/2.2): v_log_f32 + v_exp_f32 (__builtin_amdgcn_logf IS log2)
__device__ __forceinline__ float gamma22(float x){
  return __builtin_amdgcn_exp2f(0.45454545454545453f * __builtin_amdgcn_logf(x));
}

// ---- K1: decompand + split into 4 RGGB planes (2 quarter-cols/thread) + zero sums ----
__global__ __launch_bounds__(256) void k_split(const float* __restrict__ x, float* __restrict__ P,
                                               float* __restrict__ sums){
  int idx = blockIdx.x*256 + threadIdx.x;
  int i = idx >> 10, jq = (idx & 1023)*2;
  const float* r0 = x + (size_t)(2*i)*IMG_W + 2*jq;
  float4 a = *(const float4*)r0;
  float4 b = *(const float4*)(r0 + IMG_W);
  size_t o = (size_t)i*Wh + jq;
  *(float2*)(P + o)            = make_float2(decompand_black(a.x), decompand_black(a.z));
  *(float2*)(P + S + o)        = make_float2(decompand_black(a.y), decompand_black(a.w));
  *(float2*)(P + 2*(size_t)S + o) = make_float2(decompand_black(b.x), decompand_black(b.z));
  *(float2*)(P + 3*(size_t)S + o) = make_float2(decompand_black(b.y), decompand_black(b.w));
  if (blockIdx.x == 0 && threadIdx.x < 4) sums[threadIdx.x] = 0.f;
}

// ---- fused guided-filter denoise (r=2, eps=100), 2 output columns/thread ----
// a-cols k=0..5 <-> col c0-2+k ; I-cols c0-4..c0+5 (10). FAST: interior, count=25.
template<int TI, bool FAST>
__device__ __forceinline__ void denoise_col2(const float* __restrict__ in, float* __restrict__ D,
                                             int c0, int i0, float& local){
  const float inv25 = 1.0f/25.0f;
  float cw_a[6], amask[6], cw_o0 = 25.f, cw_o1 = 25.f;
  if (!FAST){
    #pragma unroll
    for (int k=0;k<6;++k){
      int pc = c0 + k - 2;
      bool ok = ((unsigned)pc < (unsigned)Wh);
      amask[k] = ok ? 1.f : 0.f;
      cw_a[k]  = ok ? (float)(min(pc+2, Wh-1) - max(pc-2, 0) + 1) : 1.f;
    }
    cw_o0 = (float)(min(c0+2, Wh-1)   - max(c0-2, 0) + 1);
    cw_o1 = (float)(min(c0+3, Wh-1)   - max(c0-1, 0) + 1);
  }

  float rh1[6][5]={{0}}, rh2[6][5]={{0}};
  float vs1[6]={0}, vs2[6]={0};
  float rha0[5]={0}, rhb0[5]={0}, rha1[5]={0}, rhb1[5]={0};
  float cI0[5]={0}, cI1[5]={0};
  float wa0=0.f, wb0=0.f, wa1=0.f, wb1=0.f;

  const float* rp = in + (size_t)(i0-4)*Wh + c0;   // loads rp[-4..5]
  float* wp = D + (size_t)i0*Wh + c0;

  #pragma unroll 4
  for (int rr=0; rr<TI+8; ++rr){
    int r = i0 - 4 + rr;
    float v[10];
    if (FAST){
      float2 p0 = *(const float2*)(rp-4);
      float2 p1 = *(const float2*)(rp-2);
      float2 p2 = *(const float2*)(rp);
      float2 p3 = *(const float2*)(rp+2);
      float2 p4 = *(const float2*)(rp+4);
      v[0]=p0.x; v[1]=p0.y; v[2]=p1.x; v[3]=p1.y; v[4]=p2.x;
      v[5]=p2.y; v[6]=p3.x; v[7]=p3.y; v[8]=p4.x; v[9]=p4.y;
    } else {
      if ((unsigned)r < (unsigned)Hh){
        #pragma unroll
        for (int d=0; d<10; ++d){
          int c = c0 + d - 4;
          v[d] = ((unsigned)c < (unsigned)Wh) ? rp[d-4] : 0.f;
        }
      } else {
        #pragma unroll
        for (int d=0; d<10; ++d) v[d]=0.f;
      }
    }
    rp += Wh;
    float sq[10];
    #pragma unroll
    for (int d=0; d<10; ++d) sq[d]=v[d]*v[d];
    float h1[6], h2[6];
    h1[0]=v[0]+v[1]+v[2]+v[3]+v[4];
    h2[0]=sq[0]+sq[1]+sq[2]+sq[3]+sq[4];
    #pragma unroll
    for (int k=1;k<6;++k){
      h1[k]=h1[k-1]-v[k-1]+v[k+4];
      h2[k]=h2[k-1]-sq[k-1]+sq[k+4];
    }
    #pragma unroll
    for (int k=0;k<6;++k){
      vs1[k]+=h1[k]-rh1[k][0];
      vs2[k]+=h2[k]-rh2[k][0];
      #pragma unroll
      for (int t=0;t<4;++t){ rh1[k][t]=rh1[k][t+1]; rh2[k][t]=rh2[k][t+1]; }
      rh1[k][4]=h1[k]; rh2[k][4]=h2[k];
    }
    #pragma unroll
    for (int t=0;t<4;++t){ cI0[t]=cI0[t+1]; cI1[t]=cI1[t+1]; }
    cI0[4]=v[4]; cI1[4]=v[5];

    if (rr >= 4){
      int q = r-2;
      float a6[6], b6[6];
      if (FAST){
        #pragma unroll
        for (int k=0;k<6;++k){
          float m   = vs1[k]*inv25;
          float var = fmaf(-m, m, vs2[k]*inv25);
          float a   = var*RCP(var + 100.0f);
          a6[k] = a; b6[k] = fmaf(-m, a, m);
        }
      } else {
        float rmask = ((unsigned)q < (unsigned)Hh) ? 1.f : 0.f;
        float rh = (float)(min(q+2, Hh-1) - max(q-2, 0) + 1);
        #pragma unroll
        for (int k=0;k<6;++k){
          float inv = RCP(rh*cw_a[k]);
          float m   = vs1[k]*inv;
          float var = fmaf(-m, m, vs2[k]*inv);
          float a   = var*RCP(var + 100.0f);
          float b   = fmaf(-m, a, m);
          a6[k] = a*amask[k]*rmask; b6[k] = b*amask[k]*rmask;
        }
      }
      float ha0 = a6[0]+a6[1]+a6[2]+a6[3]+a6[4];
      float hb0 = b6[0]+b6[1]+b6[2]+b6[3]+b6[4];
      float ha1 = ha0 - a6[0] + a6[5];
      float hb1 = hb0 - b6[0] + b6[5];
      wa0 += ha0 - rha0[0]; wb0 += hb0 - rhb0[0];
      wa1 += ha1 - rha1[0]; wb1 += hb1 - rhb1[0];
      #pragma unroll
      for (int t=0;t<4;++t){
        rha0[t]=rha0[t+1]; rhb0[t]=rhb0[t+1];
        rha1[t]=rha1[t+1]; rhb1[t]=rhb1[t+1];
      }
      rha0[4]=ha0; rhb0[4]=hb0; rha1[4]=ha1; rhb1[4]=hb1;

      if (rr >= 8){
        int ro = r-4;
        float invo0, invo1;
        if (FAST){ invo0 = inv25; invo1 = inv25; }
        else {
          float rho = (float)(min(ro+2, Hh-1) - max(ro-2, 0) + 1);
          invo0 = RCP(rho*cw_o0); invo1 = RCP(rho*cw_o1);
        }
        float d0 = fmaf(wa0*invo0, cI0[0], wb0*invo0);
        float d1 = fmaf(wa1*invo1, cI1[0], wb1*invo1);
        *(float2*)wp = make_float2(d0, d1); wp += Wh;
        local += d0 + d1;
      }
    }
  }
}

template<int TI>
__global__ __launch_bounds__(256) void k_denoise(const float* __restrict__ P4,
                                                 float* __restrict__ D4,
                                                 float* __restrict__ sums){
  const int c0 = (blockIdx.x*256 + threadIdx.x)*2;
  const int i0 = blockIdx.y*TI;
  const int pl = blockIdx.z;
  const float* __restrict__ in = P4 + (size_t)pl*S;
  float* __restrict__ D = D4 + (size_t)pl*S;
  float local = 0.f;

  // wave-uniform fast check: wave covers cols [cmin, cmin+127], touches [cmin-4, cmin+131]
  const int cmin = (blockIdx.x*256 + (threadIdx.x & ~63))*2;
  const bool rows_ok = (i0 >= 4) && (i0 + TI + 4 <= Hh);
  const bool fast = rows_ok && (cmin >= 4) && (cmin + 131 < Wh);
  if (fast) denoise_col2<TI, true >(in, D, c0, i0, local);
  else      denoise_col2<TI, false>(in, D, c0, i0, local);

  __shared__ float red[256];
  red[threadIdx.x]=local;
  __syncthreads();
  #pragma unroll
  for (int off=128; off>0; off>>=1){
    if (threadIdx.x<off) red[threadIdx.x]+=red[threadIdx.x+off];
    __syncthreads();
  }
  if (threadIdx.x==0) atomicAdd(sums+pl, red[0]);
}

// ---- LTM box pass 1 (r=8) ----
template<int R, int TI>
__global__ __launch_bounds__(256) void k_boxsq_ab(const float* __restrict__ in,
                                                  float* __restrict__ A, float* __restrict__ B,
                                                  float eps){
  int j  = blockIdx.x*256 + threadIdx.x;
  int i0 = blockIdx.y*TI;
  int cw = min(j+R, Wh-1) - max(j-R, 0) + 1;

  float hs[2*R+1], hs2[2*R+1];
  float ws = 0.f, ws2 = 0.f;
  #pragma unroll
  for (int k=0; k<2*R+1; ++k){
    int r = i0 - R + k;
    float s = 0.f, s2 = 0.f;
    if ((unsigned)r < (unsigned)Hh){
      const float* row = in + r*Wh;
      #pragma unroll
      for (int d=-R; d<=R; ++d){
        int c = j + d;
        float v = ((unsigned)c < (unsigned)Wh) ? row[c] : 0.f;
        s += v; s2 = fmaf(v, v, s2);
      }
    }
    hs[k] = s; hs2[k] = s2; ws += s; ws2 += s2;
  }
  #pragma unroll
  for (int t=0; t<TI; ++t){
    int i = i0 + t;
    int rh = min(i+R, Hh-1) - max(i-R, 0) + 1;
    float inv = 1.0f/(float)(rh*cw);
    float m   = ws*inv;
    float var = fmaf(-m, m, ws2*inv);
    float a   = var/(var + eps);
    A[i*Wh + j] = a;
    B[i*Wh + j] = m*(1.0f - a);
    if (t < TI-1){
      ws -= hs[0]; ws2 -= hs2[0];
      #pragma unroll
      for (int k=0; k<2*R; ++k){ hs[k]=hs[k+1]; hs2[k]=hs2[k+1]; }
      int r = i + R + 1;
      float s = 0.f, s2 = 0.f;
      if (r < Hh){
        const float* row = in + r*Wh;
        #pragma unroll
        for (int d=-R; d<=R; ++d){
          int c = j + d;
          float v = ((unsigned)c < (unsigned)Wh) ? row[c] : 0.f;
          s += v; s2 = fmaf(v, v, s2);
        }
      }
      hs[2*R] = s; hs2[2*R] = s2; ws += s; ws2 += s2;
    }
  }
}

// ---- LTM box pass 2 (r=8) ----
template<int R, int TI>
__global__ __launch_bounds__(256) void k_box_apply(const float* __restrict__ in,
                                                   const float* __restrict__ A, const float* __restrict__ B,
                                                   float* __restrict__ D){
  int j  = blockIdx.x*256 + threadIdx.x;
  int i0 = blockIdx.y*TI;
  int cw = min(j+R, Wh-1) - max(j-R, 0) + 1;

  float ha[2*R+1], hb[2*R+1];
  float wa = 0.f, wb = 0.f;
  #pragma unroll
  for (int k=0; k<2*R+1; ++k){
    int r = i0 - R + k;
    float sa = 0.f, sb = 0.f;
    if ((unsigned)r < (unsigned)Hh){
      const float* ra = A + r*Wh;
      const float* rb = B + r*Wh;
      #pragma unroll
      for (int d=-R; d<=R; ++d){
        int c = j + d;
        bool ok = ((unsigned)c < (unsigned)Wh);
        sa += ok ? ra[c] : 0.f;
        sb += ok ? rb[c] : 0.f;
      }
    }
    ha[k] = sa; hb[k] = sb; wa += sa; wb += sb;
  }
  #pragma unroll
  for (int t=0; t<TI; ++t){
    int i = i0 + t;
    int rh = min(i+R, Hh-1) - max(i-R, 0) + 1;
    float inv = 1.0f/(float)(rh*cw);
    D[i*Wh + j] = fmaf(wa*inv, in[i*Wh + j], wb*inv);
    if (t < TI-1){
      wa -= ha[0]; wb -= hb[0];
      #pragma unroll
      for (int k=0; k<2*R; ++k){ ha[k]=ha[k+1]; hb[k]=hb[k+1]; }
      int r = i + R + 1;
      float sa = 0.f, sb = 0.f;
      if (r < Hh){
        const float* ra = A + r*Wh;
        const float* rb = B + r*Wh;
        #pragma unroll
        for (int d2=-R; d2<=R; ++d2){
          int c = j + d2;
          bool ok = ((unsigned)c < (unsigned)Wh);
          sa += ok ? ra[c] : 0.f;
          sb += ok ? rb[c] : 0.f;
        }
      }
      ha[2*R] = sa; hb[2*R] = sb; wa += sa; wb += sb;
    }
  }
}

// ---- AWB gains from sums (wave-uniform; inlined into consumers) ----
__device__ __forceinline__ void awb_gains(const float* __restrict__ sums, float& gr, float& gb){
  const float invS = 1.0f/(float)S;
  float rm = sums[0]*invS, g1 = sums[1]*invS, g2 = sums[2]*invS, bm = sums[3]*invS;
  float gm = 0.5f*(g1+g2);
  gr = fminf(gm/(rm + 1e-8f), 4.0f);
  gb = fminf(gm/(bm + 1e-8f), 4.0f);
}

// ---- gather 4x6 mosaic window for output cols (i,j),(i,j+1), j even ----
// mosaic rows 2i-1..2i+2, cols 2j-1..2j+4. Zero-pad outside (conv 'SAME').
__device__ __forceinline__ void load_mosaic2(const float* __restrict__ D, float gr, float gb,
                                             int i, int j, float m[4][6]){
  const float* __restrict__ P0 = D;
  const float* __restrict__ P1 = D + (size_t)S;
  const float* __restrict__ P2 = D + (size_t)2*S;
  const float* __restrict__ P3 = D + (size_t)3*S;
  const bool up = (i > 0), dn = (i < Hh-1), lf = (j > 0), rt = (j+2 < Wh);
  const size_t rc = (size_t)i*Wh + j;
  const size_t ru = rc - Wh, rd = rc + Wh;
  const float2 z = make_float2(0.f, 0.f);
  // row0: y=2i-1 (odd y): P2 even-x / P3 odd-x, plane row i-1
  {
    float2 t3 = up ? *(const float2*)(P3+ru) : z;
    float2 t2 = up ? *(const float2*)(P2+ru) : z;
    m[0][0] = (up&&lf) ? clamp01(P3[ru-1]*gb) : 0.f;
    m[0][1] = clamp01(t2.x);
    m[0][2] = clamp01(t3.x*gb);
    m[0][3] = clamp01(t2.y);
    m[0][4] = clamp01(t3.y*gb);
    m[0][5] = (up&&rt) ? clamp01(P2[ru+2]) : 0.f;
  }
  // row1: y=2i (even y): P0 even-x (gr) / P1 odd-x, plane row i
  {
    float2 t1 = *(const float2*)(P1+rc);
    float2 t0 = *(const float2*)(P0+rc);
    m[1][0] = lf ? clamp01(P1[rc-1]) : 0.f;
    m[1][1] = clamp01(t0.x*gr);
    m[1][2] = clamp01(t1.x);
    m[1][3] = clamp01(t0.y*gr);
    m[1][4] = clamp01(t1.y);
    m[1][5] = rt ? clamp01(P0[rc+2]*gr) : 0.f;
  }
  // row2: y=2i+1 (odd y): P2/P3, plane row i
  {
    float2 s3 = *(const float2*)(P3+rc);
    float2 s2 = *(const float2*)(P2+rc);
    m[2][0] = lf ? clamp01(P3[rc-1]*gb) : 0.f;
    m[2][1] = clamp01(s2.x);
    m[2][2] = clamp01(s3.x*gb);
    m[2][3] = clamp01(s2.y);
    m[2][4] = clamp01(s3.y*gb);
    m[2][5] = rt ? clamp01(P2[rc+2]) : 0.f;
  }
  // row3: y=2i+2 (even y): P0/P1, plane row i+1
  {
    float2 u1 = dn ? *(const float2*)(P1+rd) : z;
    float2 u0 = dn ? *(const float2*)(P0+rd) : z;
    m[3][0] = (dn&&lf) ? clamp01(P1[rd-1]) : 0.f;
    m[3][1] = clamp01(u0.x*gr);
    m[3][2] = clamp01(u1.x);
    m[3][3] = clamp01(u0.y*gr);
    m[3][4] = clamp01(u1.y);
    m[3][5] = (dn&&rt) ? clamp01(P0[rd+2]*gr) : 0.f;
  }
}

// demosaic+CCM on a 4x4 slice of the 4x6 window, offset o*2 (o=0,1)
template<int O>
__device__ __forceinline__ void demosaic_ccm_s(const float m[4][6], const float* __restrict__ C,
                                               float R[2][2], float G[2][2], float Bv[2][2]){
  #define MM(a,b) m[a][(b)+2*O]
  float r[2][2], g[2][2], b[2][2];
  r[0][0] = MM(1,1);
  g[0][0] = 0.25f*(MM(0,1)+MM(2,1)+MM(1,0)+MM(1,2));
  b[0][0] = 0.25f*(MM(0,0)+MM(0,2)+MM(2,0)+MM(2,2));
  r[0][1] = 0.5f*(MM(1,1)+MM(1,3));
  g[0][1] = MM(1,2);
  b[0][1] = 0.5f*(MM(0,2)+MM(2,2));
  r[1][0] = 0.5f*(MM(1,1)+MM(3,1));
  g[1][0] = MM(2,1);
  b[1][0] = 0.5f*(MM(2,0)+MM(2,2));
  r[1][1] = 0.25f*(MM(1,1)+MM(1,3)+MM(3,1)+MM(3,3));
  g[1][1] = 0.25f*(MM(1,2)+MM(3,2)+MM(2,1)+MM(2,3));
  b[1][1] = MM(2,2);
  #undef MM
  #pragma unroll
  for (int a=0; a<2; ++a){
    #pragma unroll
    for (int c=0; c<2; ++c){
      R[a][c]  = clamp01(fmaf(C[2], b[a][c], fmaf(C[1], g[a][c], C[0]*r[a][c])));
      G[a][c]  = clamp01(fmaf(C[5], b[a][c], fmaf(C[4], g[a][c], C[3]*r[a][c])));
      Bv[a][c] = clamp01(fmaf(C[8], b[a][c], fmaf(C[7], g[a][c], C[6]*r[a][c])));
    }
  }
}

// ---- half-res luma Ys (2 cols/thread) ----
__global__ __launch_bounds__(256) void k_ys(const float* __restrict__ D, const float* __restrict__ sums,
                                            const float* __restrict__ C, float* __restrict__ Ys){
  int idx = blockIdx.x*256 + threadIdx.x;
  int i = idx >> 10, j = (idx & 1023)*2;
  float gr, gb; awb_gains(sums, gr, gb);
  float m[4][6]; load_mosaic2(D, gr, gb, i, j, m);
  float y0 = 0.f, y1 = 0.f;
  {
    float R[2][2], G[2][2], Bv[2][2];
    demosaic_ccm_s<0>(m, C, R, G, Bv);
    #pragma unroll
    for (int a=0; a<2; ++a)
      #pragma unroll
      for (int c=0; c<2; ++c)
        y0 += 0.299f*R[a][c] + 0.587f*G[a][c] + 0.114f*Bv[a][c];
  }
  {
    float R[2][2], G[2][2], Bv[2][2];
    demosaic_ccm_s<1>(m, C, R, G, Bv);
    #pragma unroll
    for (int a=0; a<2; ++a)
      #pragma unroll
      for (int c=0; c<2; ++c)
        y1 += 0.299f*R[a][c] + 0.587f*G[a][c] + 0.114f*Bv[a][c];
  }
  *(float2*)(Ys + (size_t)i*Wh + j) = make_float2(0.25f*y0, 0.25f*y1);
}

// ---- final: demosaic+CCM + LTM + gamma + RGB->YUV -> NV12 (2 cols/thread) ----
__global__ __launch_bounds__(256) void k_final(const float* __restrict__ D, const float* __restrict__ sums,
                                               const float* __restrict__ C,
                                               const float* __restrict__ bs, float* __restrict__ out){
  int idx = blockIdx.x*256 + threadIdx.x;
  int i = idx >> 10, j = (idx & 1023)*2;
  float gr, gb; awb_gains(sums, gr, gb);
  float m[4][6]; load_mosaic2(D, gr, gb, i, j, m);

  // bs neighborhood rows i-1..i+1, cols j-1..j+2 (clamped)
  float bsv[3][4];
  #pragma unroll
  for (int a=0; a<3; ++a){
    int r = min(max(i-1+a, 0), Hh-1);
    const float* br = bs + ((size_t)r<<11);
    bsv[a][0] = br[max(j-1, 0)];
    float2 t = *(const float2*)(br + j);
    bsv[a][1] = t.x; bsv[a][2] = t.y;
    bsv[a][3] = br[min(j+2, Wh-1)];
  }

  float Yrow0[4], Yrow1[4], UV[4];
  #pragma unroll
  for (int o=0; o<2; ++o){
    float R[2][2], G[2][2], Bv[2][2];
    if (o==0) demosaic_ccm_s<0>(m, C, R, G, Bv);
    else      demosaic_ccm_s<1>(m, C, R, G, Bv);
    // bilinear upsample of base_s around col j+o (bsv local cols o..o+2)
    float base[2][2];
    base[0][0] = 0.0625f*bsv[0][0+o] + 0.1875f*bsv[0][1+o] + 0.1875f*bsv[1][0+o] + 0.5625f*bsv[1][1+o];
    base[0][1] = 0.1875f*bsv[0][1+o] + 0.0625f*bsv[0][2+o] + 0.5625f*bsv[1][1+o] + 0.1875f*bsv[1][2+o];
    base[1][0] = 0.1875f*bsv[1][0+o] + 0.5625f*bsv[1][1+o] + 0.0625f*bsv[2][0+o] + 0.1875f*bsv[2][1+o];
    base[1][1] = 0.5625f*bsv[1][1+o] + 0.1875f*bsv[1][2+o] + 0.1875f*bsv[2][1+o] + 0.0625f*bsv[2][2+o];

    float Uacc = 0.f, Vacc = 0.f;
    #pragma unroll
    for (int a=0; a<2; ++a){
      #pragma unroll
      for (int c=0; c<2; ++c){
        float Yl   = 0.299f*R[a][c] + 0.587f*G[a][c] + 0.114f*Bv[a][c];
        float Ynew = fmaf(0.7f, base[a][c], Yl - base[a][c]);
        float sc   = Ynew/(Yl + 1e-6f);
        float Rg = gamma22(fmaxf(clamp01(R[a][c]*sc),  1e-6f));
        float Gg = gamma22(fmaxf(clamp01(G[a][c]*sc),  1e-6f));
        float Bg = gamma22(fmaxf(clamp01(Bv[a][c]*sc), 1e-6f));
        float Yf = 0.299f*Rg + 0.587f*Gg + 0.114f*Bg;
        float Yq = fminf(fmaxf(Yf*255.0f, 0.0f), 255.0f);
        if (a==0) Yrow0[2*o+c] = Yq; else Yrow1[2*o+c] = Yq;
        Uacc += -0.168736f*Rg - 0.331264f*Gg + 0.5f*Bg + 0.5f;
        Vacc +=  0.5f*Rg - 0.418688f*Gg - 0.081312f*Bg + 0.5f;
      }
    }
    UV[2*o]   = fminf(fmaxf(0.25f*Uacc*255.0f, 0.0f), 255.0f);
    UV[2*o+1] = fminf(fmaxf(0.25f*Vacc*255.0f, 0.0f), 255.0f);
  }
  *(float4*)(out + (size_t)(2*i)*IMG_W   + 2*j) = make_float4(Yrow0[0], Yrow0[1], Yrow0[2], Yrow0[3]);
  *(float4*)(out + (size_t)(2*i+1)*IMG_W + 2*j) = make_float4(Yrow1[0], Yrow1[1], Yrow1[2], Yrow1[3]);
  *(float4*)(out + (size_t)IMG_H*IMG_W + (size_t)i*IMG_W + 2*j) = make_float4(UV[0], UV[1], UV[2], UV[3]);
}

extern "C" void kernel_launch(void* const* d_in, const int* in_sizes, int n_in,
                              void* d_out, int out_size, void* d_ws, size_t ws_size,
                              hipStream_t stream){
  const float* x   = (const float*)d_in[0];
  const float* ccm = (const float*)d_in[1];
  float* ws  = (float*)d_ws;
  float* out = (float*)d_out;

  // workspace layout (floats), total 10*S + 8:
  //  [0,4S)   P (planes); free after k_denoise -> Lb=[0,S), bs=[S,2S)
  //  [4S,8S)  D (denoised planes) — live until k_final
  //  [8S,9S)  Ys
  //  [9S,10S) La
  //  [10S,+8) sums[4]
  size_t need = ((size_t)10*S + 8)*sizeof(float);
  if (ws_size < need) return;

  float* P  = ws;
  float* D  = ws + (size_t)4*S;
  float* Ys = ws + (size_t)8*S;
  float* La = ws + (size_t)9*S;
  float* Lb = ws;                    // aliases P (dead after denoise)
  float* bs = ws + (size_t)S;
  float* sums  = ws + (size_t)10*S;

  const int nb2 = S/512;                    // 2-col kernels
  dim3 gdn(Wh/512, Hh/TID, 4);              // fused denoise, all planes, 2-col
  dim3 gltm(Wh/256, Hh/TIL);                // LTM box kernels

  k_split<<<nb2, 256, 0, stream>>>(x, P, sums);
  k_denoise<TID><<<gdn, 256, 0, stream>>>(P, D, sums);
  k_ys<<<nb2, 256, 0, stream>>>(D, sums, ccm, Ys);
  k_boxsq_ab<8, TIL><<<gltm, 256, 0, stream>>>(Ys, La, Lb, 1e-3f);
  k_box_apply<8, TIL><<<gltm, 256, 0, stream>>>(Ys, La, Lb, bs);
  k_final<<<nb2, 256, 0, stream>>>(D, sums, ccm, bs, out);
}